// Round 8
// baseline (584.718 us; speedup 1.0000x reference)
//
#include <hip/hip_runtime.h>
#include <hip/hip_bf16.h>

// ExpertODEEnsemble: E=8, D=64, H=512, B=32768.
// R23 = ABLATION of the fine-grained sync machinery (R15..R22 all 371-377us,
// MfmaUtil pinned 37-39% across three different flag topologies; depth-2
// A-prefetch exact null killed the latency theory).
//   - ALL flags/atomics/spin-polls/sched_barriers/setprio REMOVED.
//   - 6 x __syncthreads() per expert: [reads] barrier [epi_write] barrier.
//     Barrier between reads and writes makes in-place act overwrite safe ->
//     fixed act layout (wave w writes slabs 4w..4w+3), no rotation/slots.
//   - Inner loops are branch-free flat streams (next-A + next-B prefetch,
//     8 MFMAs) — no fences, compiler schedules freely for the first time.
//   - Tile structure, ws layout, prep_kernel, epilogue math: R15-identical.
// Decisive branches: ~300us => flag machinery was the stall;
//                    ~375us => sync exonerated, next lever is occupancy.

typedef unsigned short ushort_t;
typedef unsigned int u32;
typedef unsigned long long u64;
typedef __attribute__((ext_vector_type(8))) short short8;
typedef __attribute__((ext_vector_type(4))) float floatx4;
typedef __attribute__((ext_vector_type(16))) float floatx16;
typedef __attribute__((ext_vector_type(4))) int intx4;

// ws layout (bytes); granule = 16 B = 8 bf16 along k (unchanged from R15)
#define W1A_OFF 0u          // per e (65536 B): granule ((w*4+kc)*2+ol)*64+lane
#define W2A_OFF 524288u     // per e (524288B): granule ((w*32+kc)*2+ol)*64+lane
#define W3A_OFF 4718592u
#define W4A_OFF 8912896u    // per e (65536 B): granule (o4*32+kc)*64+lane
#define XB_OFF  9437184u    // x row-major bf16 [32768][64]
#define B1E_OFF 13631488u   // b1_eff fp32 [8][512]

// LDS: act 32 slabs * 4096 = 131072; x 4 slabs * 4096 = 16384
#define X_OFF_L 131072
#define SMEM_SZ 147456

static __device__ __forceinline__ u32 pk2bf(float a, float b) {
  union { __hip_bfloat162 h; u32 u; } v;
  v.h = __float22bfloat162_rn(make_float2(a, b));
  return v.u;
}

static __device__ __forceinline__ float pade_tanh(float x) {
  // tanh x = x(945+105x^2+x^4)/(945+420x^2+15x^4); |err|<=1e-4 for |x|<=2
  float x2 = x * x;
  float num = __builtin_fmaf(x2, __builtin_fmaf(x2, 1.0f, 105.0f), 945.0f);
  float den = __builtin_fmaf(x2, __builtin_fmaf(x2, 15.0f, 420.0f), 945.0f);
  return x * num * __builtin_amdgcn_rcpf(den);
}

static __device__ __forceinline__ void ald16(const void* g, void* l) {
  __builtin_amdgcn_global_load_lds((__attribute__((address_space(1))) void*)g,
                                   (__attribute__((address_space(3))) void*)l,
                                   16, 0, 0);
}

static __device__ __forceinline__ floatx16 mfma32(short8 a, short8 b, floatx16 c) {
  return __builtin_amdgcn_mfma_f32_32x32x16_bf16(a, b, c, 0, 0, 0);
}

// ------ prep: thread == dest granule (lane-fastest) -> coalesced writes ------
// (byte-identical to R15)
__global__ __launch_bounds__(256) void prep_kernel(
    const float* __restrict__ t, const float* __restrict__ x,
    const float* __restrict__ omega, const float* __restrict__ W1,
    const float* __restrict__ b1, const float* __restrict__ W2,
    const float* __restrict__ W3, const float* __restrict__ W4,
    char* __restrict__ ws) {
  int i = blockIdx.x * 256 + threadIdx.x;
  if (i < 32768) {                       // W1A: d=((w*4+kc)*2+ol)*64+lane
    int e = i >> 12, d = i & 4095;
    int lane = d & 63, q = d >> 6;
    int ol = q & 1, kc = (q >> 1) & 3, w = q >> 3;
    int outr = w * 64 + ol * 32 + (lane & 31);
    int kg = kc * 2 + (lane >> 5);
    const float* s = W1 + (e * 512 + outr) * 67 + kg * 8;   // stride 67: scalar
    ((intx4*)(ws + W1A_OFF))[i] = (intx4){
        (int)pk2bf(s[0], s[1]), (int)pk2bf(s[2], s[3]),
        (int)pk2bf(s[4], s[5]), (int)pk2bf(s[6], s[7])};
    return;
  }
  i -= 32768;
  if (i < 262144) {                      // W2A: d=((w*32+kc)*2+ol)*64+lane
    int e = i >> 15, d = i & 32767;
    int lane = d & 63, q = d >> 6;
    int ol = q & 1, kc = (q >> 1) & 31, w = q >> 6;
    int outr = w * 64 + ol * 32 + (lane & 31);
    int kg = kc * 2 + (lane >> 5);
    const floatx4* s = (const floatx4*)(W2 + ((e << 9) + outr) * 512 + (kg << 3));
    floatx4 lo = s[0], hi = s[1];
    ((intx4*)(ws + W2A_OFF))[i] = (intx4){
        (int)pk2bf(lo[0], lo[1]), (int)pk2bf(lo[2], lo[3]),
        (int)pk2bf(hi[0], hi[1]), (int)pk2bf(hi[2], hi[3])};
    return;
  }
  i -= 262144;
  if (i < 262144) {                      // W3A
    int e = i >> 15, d = i & 32767;
    int lane = d & 63, q = d >> 6;
    int ol = q & 1, kc = (q >> 1) & 31, w = q >> 6;
    int outr = w * 64 + ol * 32 + (lane & 31);
    int kg = kc * 2 + (lane >> 5);
    const floatx4* s = (const floatx4*)(W3 + ((e << 9) + outr) * 512 + (kg << 3));
    floatx4 lo = s[0], hi = s[1];
    ((intx4*)(ws + W3A_OFF))[i] = (intx4){
        (int)pk2bf(lo[0], lo[1]), (int)pk2bf(lo[2], lo[3]),
        (int)pk2bf(hi[0], hi[1]), (int)pk2bf(hi[2], hi[3])};
    return;
  }
  i -= 262144;
  if (i < 32768) {                       // W4A: d=(o4*32+kc)*64+lane
    int e = i >> 12, d = i & 4095;
    int lane = d & 63, q = d >> 6;
    int kc = q & 31, o4 = q >> 5;
    int outr = o4 * 32 + (lane & 31);
    int kg = kc * 2 + (lane >> 5);
    const floatx4* s = (const floatx4*)(W4 + ((e << 6) + outr) * 512 + (kg << 3));
    floatx4 lo = s[0], hi = s[1];
    ((intx4*)(ws + W4A_OFF))[i] = (intx4){
        (int)pk2bf(lo[0], lo[1]), (int)pk2bf(lo[2], lo[3]),
        (int)pk2bf(hi[0], hi[1]), (int)pk2bf(hi[2], hi[3])};
    return;
  }
  i -= 32768;
  if (i < 262144) {                      // x -> bf16 (coalesced both ways)
    const floatx4* s = (const floatx4*)(x + i * 8);
    floatx4 lo = s[0], hi = s[1];
    ((intx4*)(ws + XB_OFF))[i] = (intx4){
        (int)pk2bf(lo[0], lo[1]), (int)pk2bf(lo[2], lo[3]),
        (int)pk2bf(hi[0], hi[1]), (int)pk2bf(hi[2], hi[3])};
    return;
  }
  i -= 262144;
  if (i < 4096) {                        // b1_eff
    float tv = t[0];
    int e = i >> 9;
    float om = omega[e];
    ((float*)(ws + B1E_OFF))[i] = b1[i] + tv * W1[i * 67 + 64]
        + sinf(om * tv) * W1[i * 67 + 65] + cosf(om * tv) * W1[i * 67 + 66];
  }
}

// slab (4096 B): nt*1024 + (k16half*32 + r31)*16 + q1*8 (write side);
// read side: chunk nt at slab + nt*1024 + lane*16 — identical pair to R15.

static __device__ __forceinline__ void epi_write(
    floatx16 acc[2][4], char* __restrict__ act, int wbyte, int r31, int q1) {
#pragma unroll
  for (int ol = 0; ol < 2; ++ol) {
#pragma unroll
    for (int g = 0; g < 4; ++g) {
      int ko = ol * 4 + g;
      char* base = act + wbyte + (ko >> 1) * 4096
                   + (((ko & 1) * 32 + r31) << 4) + q1 * 8;
#pragma unroll
      for (int nt = 0; nt < 4; ++nt) {
        float v0 = pade_tanh(acc[ol][nt][4 * g + 0]);
        float v1 = pade_tanh(acc[ol][nt][4 * g + 1]);
        float v2 = pade_tanh(acc[ol][nt][4 * g + 2]);
        float v3 = pade_tanh(acc[ol][nt][4 * g + 3]);
        u32 lo = pk2bf(v0, v1), hi = pk2bf(v2, v3);
        *(u64*)(base + nt * 1024) = ((u64)hi << 32) | lo;
      }
    }
  }
}

// One MLP layer, barrier-synced, branch-free flat K-stream.
// Wave w: feats [64w, 64w+64) (2 frags), rows = all 128 (4 nt).
// bsrc = input (act or xreg, NKC slabs); writes own slabs (wave w -> 4w..4w+3).
template <int NKC, int UNR>
static __device__ __forceinline__ void mlp_layer_bar(
    const char* __restrict__ bsrc, char* __restrict__ act,
    int lane, int w, int q1, int r31,
    const char* __restrict__ Abase, const float* __restrict__ bias) {
  const int voff = lane * 16;
  const char* apW = Abase + w * (NKC * 2048) + voff;

  floatx16 acc[2][4];
#pragma unroll
  for (int ol = 0; ol < 2; ++ol) {
    int fe0 = w * 64 + ol * 32 + 4 * q1;
#pragma unroll
    for (int g = 0; g < 4; ++g) {
      floatx4 bv = *(const floatx4*)(bias + fe0 + 8 * g);
#pragma unroll
      for (int nt = 0; nt < 4; ++nt) {
        acc[ol][nt][4 * g + 0] = bv[0];
        acc[ol][nt][4 * g + 1] = bv[1];
        acc[ol][nt][4 * g + 2] = bv[2];
        acc[ol][nt][4 * g + 3] = bv[3];
      }
    }
  }
  // prologue: kc=0
  short8 a0 = *(const short8*)(apW);
  short8 a1 = *(const short8*)(apW + 1024);
  const char* bp = bsrc + voff;
  short8 b0 = *(const short8*)(bp);
  short8 b1v = *(const short8*)(bp + 1024);
  short8 b2 = *(const short8*)(bp + 2048);
  short8 b3 = *(const short8*)(bp + 3072);

#pragma unroll UNR
  for (int kc = 0; kc < NKC; ++kc) {
    int kn = (kc + 1 < NKC) ? (kc + 1) : kc;   // clamp: last step dead reload
    const char* apn = apW + kn * 2048;
    const char* bpn = bsrc + kn * 4096 + voff;
    short8 an0 = *(const short8*)(apn);
    short8 an1 = *(const short8*)(apn + 1024);
    short8 bn0 = *(const short8*)(bpn);
    short8 bn1 = *(const short8*)(bpn + 1024);
    short8 bn2 = *(const short8*)(bpn + 2048);
    short8 bn3 = *(const short8*)(bpn + 3072);
    acc[0][0] = mfma32(a0, b0, acc[0][0]);
    acc[0][1] = mfma32(a0, b1v, acc[0][1]);
    acc[0][2] = mfma32(a0, b2, acc[0][2]);
    acc[0][3] = mfma32(a0, b3, acc[0][3]);
    acc[1][0] = mfma32(a1, b0, acc[1][0]);
    acc[1][1] = mfma32(a1, b1v, acc[1][1]);
    acc[1][2] = mfma32(a1, b2, acc[1][2]);
    acc[1][3] = mfma32(a1, b3, acc[1][3]);
    a0 = an0; a1 = an1;
    b0 = bn0; b1v = bn1; b2 = bn2; b3 = bn3;
  }
  __syncthreads();                       // all waves done READING input act
  epi_write(acc, act, w * 16384, r31, q1);
  __syncthreads();                       // all writes visible
}

extern "C" __global__ __launch_bounds__(512) void fused_kernel(
    const char* __restrict__ ws, const float* __restrict__ b2,
    const float* __restrict__ b3, const float* __restrict__ b4,
    const float* __restrict__ ew, float* __restrict__ out) {
  extern __shared__ char smem[];
  char* act = smem;
  char* xreg = smem + X_OFF_L;

  const int t = threadIdx.x, lane = t & 63, w = t >> 6;   // 8 waves
  const int q1 = lane >> 5, r31 = lane & 31;
  const int row0 = blockIdx.x << 7;      // 128-row tile, 256 blocks (1/CU)
  const int voff = lane * 16;

  // stage x: 16 units of 1KB; unit u: x-slab u>>2, nt u&3 (stride 4096)
  const ushort_t* xb = (const ushort_t*)(ws + XB_OFF);
#pragma unroll
  for (int s = 0; s < 2; ++s) {
    int u = w + 8 * s, v = u >> 2, nt = u & 3;
    ald16(xb + (row0 + nt * 32 + r31) * 64 + (2 * v + q1) * 8,
          xreg + v * 4096 + nt * 1024);
  }
  __syncthreads();                       // x staged

  const int rt = w & 3, kh = w >> 2;     // L4: row-tile, K-half
  const int row_l4 = row0 + rt * 32 + r31;
  floatx16 oacc[2] = {};

  for (int e = 0; e < 8; ++e) {
    // L1 (K=64, B from x; epi overwrite safe: its pre-write barrier covers
    // every wave's L4(e-1) reads in program order)
    mlp_layer_bar<4, 4>(xreg, act, lane, w, q1, r31,
                        (const char*)ws + W1A_OFF + e * 65536,
                        (const float*)(ws + B1E_OFF) + e * 512);
    // L2, L3 (K=512)
    mlp_layer_bar<32, 4>(act, act, lane, w, q1, r31,
                         (const char*)ws + W2A_OFF + e * 524288, b2 + e * 512);
    mlp_layer_bar<32, 4>(act, act, lane, w, q1, r31,
                         (const char*)ws + W3A_OFF + e * 524288, b3 + e * 512);

    // L4: M=64 (both o4), N=32 (rows rt), K-half kh; flat 16-kc stream;
    // no act writes, no barrier (next L1's pre-write barrier covers reads).
    {
      const char* spA4 = (const char*)ws + W4A_OFF + e * 65536 + voff;
      const float sc = ew[row_l4 * 8 + e];
      floatx16 acc4[2] = {};
      const int s0 = kh * 16;
      const char* ap = spA4 + s0 * 1024;             // o4=0 stream
      const char* bp = act + s0 * 4096 + rt * 1024 + voff;
      short8 a0 = *(const short8*)(ap);
      short8 a1 = *(const short8*)(ap + 32768);      // o4=1 stream
      short8 b = *(const short8*)(bp);
#pragma unroll 4
      for (int kc = 0; kc < 16; ++kc) {
        int kn = (kc + 1 < 16) ? (kc + 1) : kc;      // clamp: dead reload
        const char* apn = spA4 + (s0 + kn) * 1024;
        const char* bpn = act + (s0 + kn) * 4096 + rt * 1024 + voff;
        short8 an0 = *(const short8*)(apn);
        short8 an1 = *(const short8*)(apn + 32768);
        short8 bn = *(const short8*)(bpn);
        acc4[0] = mfma32(a0, b, acc4[0]);
        acc4[1] = mfma32(a1, b, acc4[1]);
        a0 = an0; a1 = an1; b = bn;
      }
      if (kh == 0) {
        const float* bp4 = b4 + e * 64;
#pragma unroll
        for (int ol = 0; ol < 2; ++ol) {
          int fe0 = ol * 32 + 4 * q1;
#pragma unroll
          for (int g2 = 0; g2 < 4; ++g2) {
            floatx4 bv = *(const floatx4*)(bp4 + fe0 + 8 * g2);
            oacc[ol][4 * g2 + 0] += sc * (acc4[ol][4 * g2 + 0] + bv[0]);
            oacc[ol][4 * g2 + 1] += sc * (acc4[ol][4 * g2 + 1] + bv[1]);
            oacc[ol][4 * g2 + 2] += sc * (acc4[ol][4 * g2 + 2] + bv[2]);
            oacc[ol][4 * g2 + 3] += sc * (acc4[ol][4 * g2 + 3] + bv[3]);
          }
        }
      } else {
#pragma unroll
        for (int ol = 0; ol < 2; ++ol)
#pragma unroll
          for (int i = 0; i < 16; ++i) oacc[ol][i] += sc * acc4[ol][i];
      }
    }
  }

  // final: merge K-half partners (w, w+4) via LDS (act dead), plain stores
  __syncthreads();
  if (kh == 1) {
#pragma unroll
    for (int ol = 0; ol < 2; ++ol)
#pragma unroll
      for (int g = 0; g < 4; ++g) {
        floatx4 p = {oacc[ol][4 * g + 0], oacc[ol][4 * g + 1],
                     oacc[ol][4 * g + 2], oacc[ol][4 * g + 3]};
        *(floatx4*)(act + rt * 8192 + ol * 4096 + g * 1024 + lane * 16) = p;
      }
  }
  __syncthreads();
  if (kh == 0) {
    float* orow = out + (size_t)row_l4 * 64;
#pragma unroll
    for (int ol = 0; ol < 2; ++ol)
#pragma unroll
      for (int g = 0; g < 4; ++g) {
        floatx4 p = *(const floatx4*)(act + rt * 8192 + ol * 4096 + g * 1024 + lane * 16);
        floatx4 v = {oacc[ol][4 * g + 0] + p[0], oacc[ol][4 * g + 1] + p[1],
                     oacc[ol][4 * g + 2] + p[2], oacc[ol][4 * g + 3] + p[3]};
        *(floatx4*)(orow + ol * 32 + 8 * g + 4 * q1) = v;
      }
  }
}

extern "C" void kernel_launch(void* const* d_in, const int* in_sizes, int n_in,
                              void* d_out, int out_size, void* d_ws, size_t ws_size,
                              hipStream_t stream) {
  const float* t  = (const float*)d_in[0];
  const float* x  = (const float*)d_in[1];
  const float* ew = (const float*)d_in[2];
  const float* om = (const float*)d_in[3];
  const float* W1 = (const float*)d_in[4];
  const float* b1 = (const float*)d_in[5];
  const float* W2 = (const float*)d_in[6];
  const float* b2 = (const float*)d_in[7];
  const float* W3 = (const float*)d_in[8];
  const float* b3 = (const float*)d_in[9];
  const float* W4 = (const float*)d_in[10];
  const float* b4 = (const float*)d_in[11];
  char* ws = (char*)d_ws;
  float* out = (float*)d_out;
  (void)in_sizes; (void)n_in; (void)ws_size; (void)out_size;

  static int smem_set = 0;
  if (!smem_set) {
    hipFuncSetAttribute((const void*)fused_kernel,
                        hipFuncAttributeMaxDynamicSharedMemorySize, SMEM_SZ);
    smem_set = 1;
  }
  // no memset: fused_kernel writes every element of out with plain stores
  prep_kernel<<<3344, 256, 0, stream>>>(t, x, om, W1, b1, W2, W3, W4, ws);
  fused_kernel<<<256, 512, SMEM_SZ, stream>>>(ws, b2, b3, b4, ew, out);
}

// Round 9
// 442.368 us; speedup vs baseline: 1.3218x; 1.3218x over previous
//
#include <hip/hip_runtime.h>
#include <hip/hip_bf16.h>

// ExpertODEEnsemble: E=8, D=64, H=512, B=32768.
// R24 = R21 + manual counted-vmcnt A-pipeline (T4; single change).
//   Diagnosis: fine-sync variants all 371-377us; barrier ablation (R23) 523us
//   -> sync exonerated. R22 depth-2 EXACT null => compiler-neutralized:
//   hipcc emits conservative vmcnt before the MFMA cluster, draining the
//   just-issued prefetch loads -> every j-step pays full VMEM latency
//   (wall ~1340cy) at any source-level depth.
//   Fix: A-loads via inline-asm global_load_dwordx4 (invisible to compiler
//   waitcnt insertion), explicit "s_waitcnt vmcnt(4)" (2 pairs in flight)
//   + sched_barrier(0) (rule #18) before the MFMAs; pinned vmcnt(0) drain
//   after each k-loop (in-flight asm loads must not have regs reused).
//   B stays C++/ds_read (compiler lgkmcnt is fine-grained). All sync/guards/
//   rotation/stagger/epilogue byte-identical to R21 (374us, verified).

typedef unsigned short ushort_t;
typedef unsigned int u32;
typedef unsigned long long u64;
typedef __attribute__((ext_vector_type(8))) short short8;
typedef __attribute__((ext_vector_type(4))) float floatx4;
typedef __attribute__((ext_vector_type(16))) float floatx16;
typedef __attribute__((ext_vector_type(4))) int intx4;

// ws layout (bytes); granule = 16 B = 8 bf16 along k (unchanged from R15)
#define W1A_OFF 0u          // per e (65536 B): granule ((w*4+kc)*2+ol)*64+lane
#define W2A_OFF 524288u     // per e (524288B): granule ((w*32+kc)*2+ol)*64+lane
#define W3A_OFF 4718592u
#define W4A_OFF 8912896u    // per e (65536 B): granule (o4*32+kc)*64+lane
#define XB_OFF  9437184u    // x row-major bf16 [32768][64]
#define B1E_OFF 13631488u   // b1_eff fp32 [8][512]

// LDS: 8 slot-groups * 4 slabs * 4096 = 131072; x 4 slabs * 4096 = 16384;
// sync: l4c[8], pub[8], grp[8]
#define SLOTB 16384
#define X_OFF_L 131072
#define SYNC_OFF 147456
#define SMEM_SZ 147552

static __device__ __forceinline__ u32 pk2bf(float a, float b) {
  union { __hip_bfloat162 h; u32 u; } v;
  v.h = __float22bfloat162_rn(make_float2(a, b));
  return v.u;
}

static __device__ __forceinline__ float pade_tanh(float x) {
  // tanh x = x(945+105x^2+x^4)/(945+420x^2+15x^4); |err|<=1e-4 for |x|<=2
  float x2 = x * x;
  float num = __builtin_fmaf(x2, __builtin_fmaf(x2, 1.0f, 105.0f), 945.0f);
  float den = __builtin_fmaf(x2, __builtin_fmaf(x2, 15.0f, 420.0f), 945.0f);
  return x * num * __builtin_amdgcn_rcpf(den);
}

static __device__ __forceinline__ void ald16(const void* g, void* l) {
  __builtin_amdgcn_global_load_lds((__attribute__((address_space(1))) void*)g,
                                   (__attribute__((address_space(3))) void*)l,
                                   16, 0, 0);
}

static __device__ __forceinline__ floatx16 mfma32(short8 a, short8 b, floatx16 c) {
  return __builtin_amdgcn_mfma_f32_32x32x16_bf16(a, b, c, 0, 0, 0);
}

// ---- manual A-pipeline primitives ----
// asm load: invisible to compiler waitcnt insertion; issue order preserved
// among volatile asm.
static __device__ __forceinline__ short8 agl(const char* p) {
  short8 d;
  __asm__ __volatile__("global_load_dwordx4 %0, %1, off"
                       : "=&v"(d) : "v"(p));
  return d;
}
// counted wait: all but the newest 4 VMEM loads retired (= 2 pairs in
// flight). sched_barrier(0) stops hipcc hoisting MFMAs past it (rule #18).
#define VMWAIT4()                                                   \
  do {                                                              \
    __asm__ __volatile__("s_waitcnt vmcnt(4)" ::: "memory");        \
    __builtin_amdgcn_sched_barrier(0);                              \
  } while (0)
// drain with liveness pins: the 2 in-flight pairs' dest regs must stay
// allocated until the hardware write lands.
static __device__ __forceinline__ void vmdrain4(short8 a, short8 b,
                                                short8 c, short8 d) {
  __asm__ __volatile__("s_waitcnt vmcnt(0)"
                       :: "v"(a), "v"(b), "v"(c), "v"(d) : "memory");
}

// byte offset of slot for group g with layer base b (b = layer index & 7)
static __device__ __forceinline__ int slot8(int g, int b) {
  return ((g + b) & 7) * SLOTB;
}

// spin until *p >= tgt (LDS flag; all lanes read same addr -> broadcast)
static __device__ __forceinline__ void waitge(const int* p, int tgt) {
  while (*(volatile const int*)p < tgt) __builtin_amdgcn_s_sleep(1);
  __asm__ __volatile__("" ::: "memory");
}

// wait 4 contiguous flags >= tgt (16B vector read; clobber forces re-read)
static __device__ __forceinline__ void waitge4(const int* p, int tgt) {
  for (;;) {
    __asm__ __volatile__("" ::: "memory");
    intx4 v = *(const intx4*)p;
    if (v[0] >= tgt && v[1] >= tgt && v[2] >= tgt && v[3] >= tgt) break;
    __builtin_amdgcn_s_sleep(1);
  }
  __asm__ __volatile__("" ::: "memory");
}

// guard before overwriting own-input group (w+1)&7: for d=1..7 require
// grp[(w+d)&7] >= base + d (reader at step d-1 of its reverse rotation done).
static __device__ __forceinline__ void guard_grp(const int* grp, int w, int base) {
  int tg0 = base + ((0 - w - 1) & 7) + 1;
  int tg1 = base + ((1 - w - 1) & 7) + 1;
  int tg2 = base + ((2 - w - 1) & 7) + 1;
  int tg3 = base + ((3 - w - 1) & 7) + 1;
  int tg4 = base + ((4 - w - 1) & 7) + 1;
  int tg5 = base + ((5 - w - 1) & 7) + 1;
  int tg6 = base + ((6 - w - 1) & 7) + 1;
  int tg7 = base + ((7 - w - 1) & 7) + 1;
  for (;;) {
    __asm__ __volatile__("" ::: "memory");
    intx4 a = *(const intx4*)grp;
    intx4 b = *(const intx4*)(grp + 4);
    if (a[0] >= tg0 && a[1] >= tg1 && a[2] >= tg2 && a[3] >= tg3 &&
        b[0] >= tg4 && b[1] >= tg5 && b[2] >= tg6 && b[3] >= tg7) break;
    __builtin_amdgcn_s_sleep(1);
  }
  __asm__ __volatile__("" ::: "memory");
}

// publish after ds_writes: drain own LDS ops, then one lane bumps
static __device__ __forceinline__ void bump(int* p, int lane) {
  __asm__ __volatile__("s_waitcnt lgkmcnt(0)" ::: "memory");
  if (lane == 0) atomicAdd(p, 1);
}

// signal "reads done": consuming MFMAs already forced completion of the
// protected ds_reads; sched_barrier pins the atomic after them.
static __device__ __forceinline__ void bump_sig(int* p, int lane) {
  __builtin_amdgcn_sched_barrier(0);
  if (lane == 0) atomicAdd(p, 1);
}

// ------ prep: thread == dest granule (lane-fastest) -> coalesced writes ------
// (byte-identical to R15)
__global__ __launch_bounds__(256) void prep_kernel(
    const float* __restrict__ t, const float* __restrict__ x,
    const float* __restrict__ omega, const float* __restrict__ W1,
    const float* __restrict__ b1, const float* __restrict__ W2,
    const float* __restrict__ W3, const float* __restrict__ W4,
    char* __restrict__ ws) {
  int i = blockIdx.x * 256 + threadIdx.x;
  if (i < 32768) {                       // W1A: d=((w*4+kc)*2+ol)*64+lane
    int e = i >> 12, d = i & 4095;
    int lane = d & 63, q = d >> 6;
    int ol = q & 1, kc = (q >> 1) & 3, w = q >> 3;
    int outr = w * 64 + ol * 32 + (lane & 31);
    int kg = kc * 2 + (lane >> 5);
    const float* s = W1 + (e * 512 + outr) * 67 + kg * 8;   // stride 67: scalar
    ((intx4*)(ws + W1A_OFF))[i] = (intx4){
        (int)pk2bf(s[0], s[1]), (int)pk2bf(s[2], s[3]),
        (int)pk2bf(s[4], s[5]), (int)pk2bf(s[6], s[7])};
    return;
  }
  i -= 32768;
  if (i < 262144) {                      // W2A: d=((w*32+kc)*2+ol)*64+lane
    int e = i >> 15, d = i & 32767;
    int lane = d & 63, q = d >> 6;
    int ol = q & 1, kc = (q >> 1) & 31, w = q >> 6;
    int outr = w * 64 + ol * 32 + (lane & 31);
    int kg = kc * 2 + (lane >> 5);
    const floatx4* s = (const floatx4*)(W2 + ((e << 9) + outr) * 512 + (kg << 3));
    floatx4 lo = s[0], hi = s[1];
    ((intx4*)(ws + W2A_OFF))[i] = (intx4){
        (int)pk2bf(lo[0], lo[1]), (int)pk2bf(lo[2], lo[3]),
        (int)pk2bf(hi[0], hi[1]), (int)pk2bf(hi[2], hi[3])};
    return;
  }
  i -= 262144;
  if (i < 262144) {                      // W3A
    int e = i >> 15, d = i & 32767;
    int lane = d & 63, q = d >> 6;
    int ol = q & 1, kc = (q >> 1) & 31, w = q >> 6;
    int outr = w * 64 + ol * 32 + (lane & 31);
    int kg = kc * 2 + (lane >> 5);
    const floatx4* s = (const floatx4*)(W3 + ((e << 9) + outr) * 512 + (kg << 3));
    floatx4 lo = s[0], hi = s[1];
    ((intx4*)(ws + W3A_OFF))[i] = (intx4){
        (int)pk2bf(lo[0], lo[1]), (int)pk2bf(lo[2], lo[3]),
        (int)pk2bf(hi[0], hi[1]), (int)pk2bf(hi[2], hi[3])};
    return;
  }
  i -= 262144;
  if (i < 32768) {                       // W4A: d=(o4*32+kc)*64+lane
    int e = i >> 12, d = i & 4095;
    int lane = d & 63, q = d >> 6;
    int kc = q & 31, o4 = q >> 5;
    int outr = o4 * 32 + (lane & 31);
    int kg = kc * 2 + (lane >> 5);
    const floatx4* s = (const floatx4*)(W4 + ((e << 6) + outr) * 512 + (kg << 3));
    floatx4 lo = s[0], hi = s[1];
    ((intx4*)(ws + W4A_OFF))[i] = (intx4){
        (int)pk2bf(lo[0], lo[1]), (int)pk2bf(lo[2], lo[3]),
        (int)pk2bf(hi[0], hi[1]), (int)pk2bf(hi[2], hi[3])};
    return;
  }
  i -= 32768;
  if (i < 262144) {                      // x -> bf16 (coalesced both ways)
    const floatx4* s = (const floatx4*)(x + i * 8);
    floatx4 lo = s[0], hi = s[1];
    ((intx4*)(ws + XB_OFF))[i] = (intx4){
        (int)pk2bf(lo[0], lo[1]), (int)pk2bf(lo[2], lo[3]),
        (int)pk2bf(hi[0], hi[1]), (int)pk2bf(hi[2], hi[3])};
    return;
  }
  i -= 262144;
  if (i < 4096) {                        // b1_eff
    float tv = t[0];
    int e = i >> 9;
    float om = omega[e];
    ((float*)(ws + B1E_OFF))[i] = b1[i] + tv * W1[i * 67 + 64]
        + sinf(om * tv) * W1[i * 67 + 65] + cosf(om * tv) * W1[i * 67 + 66];
  }
}

// slab (4096 B): nt*1024 + ((k16half)*32 + r31)*16 + q1*8 (write side);
// read side: chunk nt at +nt*1024 + lane*16 — identical pair to R15.

static __device__ __forceinline__ void epi_write(
    floatx16 acc[2][4], char* __restrict__ act, int wbyte, int r31, int q1) {
#pragma unroll
  for (int ol = 0; ol < 2; ++ol) {
#pragma unroll
    for (int g = 0; g < 4; ++g) {
      int ko = ol * 4 + g;
      char* base = act + wbyte + (ko >> 1) * 4096
                   + (((ko & 1) * 32 + r31) << 4) + q1 * 8;
#pragma unroll
      for (int nt = 0; nt < 4; ++nt) {
        float v0 = pade_tanh(acc[ol][nt][4 * g + 0]);
        float v1 = pade_tanh(acc[ol][nt][4 * g + 1]);
        float v2 = pade_tanh(acc[ol][nt][4 * g + 2]);
        float v3 = pade_tanh(acc[ol][nt][4 * g + 3]);
        u32 lo = pk2bf(v0, v1), hi = pk2bf(v2, v3);
        *(u64*)(base + nt * 1024) = ((u64)hi << 32) | lo;
      }
    }
  }
}

// L1: B from x in LDS (4 slabs); asm A-pipeline; guard vs L4(e-1) readers.
static __device__ __forceinline__ void mlp_l1(
    char* __restrict__ act, const char* __restrict__ xreg,
    int* pub, int* l4c, int lane, int w, int q1, int r31,
    const char* __restrict__ Abase, const float* __restrict__ bias,
    int wbyte, int e) {
  const int voff = lane * 16;
  const char* ap = Abase + w * 8192 + voff;   // 4 kc, stride 2048

  floatx16 acc[2][4];
#pragma unroll
  for (int ol = 0; ol < 2; ++ol) {
    int fe0 = w * 64 + ol * 32 + 4 * q1;
#pragma unroll
    for (int g = 0; g < 4; ++g) {
      floatx4 bv = *(const floatx4*)(bias + fe0 + 8 * g);
#pragma unroll
      for (int nt = 0; nt < 4; ++nt) {
        acc[ol][nt][4 * g + 0] = bv[0];
        acc[ol][nt][4 * g + 1] = bv[1];
        acc[ol][nt][4 * g + 2] = bv[2];
        acc[ol][nt][4 * g + 3] = bv[3];
      }
    }
  }
  const char* xb0 = xreg + voff;
  short8 b0 = *(const short8*)(xb0);
  short8 b1v = *(const short8*)(xb0 + 1024);
  short8 b2 = *(const short8*)(xb0 + 2048);
  short8 b3 = *(const short8*)(xb0 + 3072);
  // asm A prologue: steps 0,1 (2 pairs in flight)
  short8 aC0 = agl(ap);
  short8 aC1 = agl(ap + 1024);
  short8 aN0 = agl(ap + 2048);
  short8 aN1 = agl(ap + 3072);

#pragma unroll
  for (int j = 0; j < 4; ++j) {
    const char* apP = ap + (j + 2) * 2048;         // j>=2: dead, in-ws
    short8 aM0 = agl(apP);
    short8 aM1 = agl(apP + 1024);
    int jn = (j < 3) ? (j + 1) : 3;                // clamp (dead at j=3)
    const char* xn = xreg + jn * 4096 + voff;
    short8 bn0 = *(const short8*)(xn);
    short8 bn1 = *(const short8*)(xn + 1024);
    short8 bn2 = *(const short8*)(xn + 2048);
    short8 bn3 = *(const short8*)(xn + 3072);
    VMWAIT4();                                     // step-j pair retired
    __builtin_amdgcn_s_setprio(1);
    acc[0][0] = mfma32(aC0, b0, acc[0][0]);
    acc[0][1] = mfma32(aC0, b1v, acc[0][1]);
    acc[0][2] = mfma32(aC0, b2, acc[0][2]);
    acc[0][3] = mfma32(aC0, b3, acc[0][3]);
    acc[1][0] = mfma32(aC1, b0, acc[1][0]);
    acc[1][1] = mfma32(aC1, b1v, acc[1][1]);
    acc[1][2] = mfma32(aC1, b2, acc[1][2]);
    acc[1][3] = mfma32(aC1, b3, acc[1][3]);
    __builtin_amdgcn_s_setprio(0);
    aC0 = aN0; aC1 = aN1; aN0 = aM0; aN1 = aM1;
    b0 = bn0; b1v = bn1; b2 = bn2; b3 = bn3;
  }
  vmdrain4(aC0, aC1, aN0, aN1);          // in-flight dead pairs land
  // overwrite guard: victim = L3(e-1) output group (w+1)&7, read by L4(e-1)
  if (e > 0) waitge4(l4c + ((((w + 1) & 7) >> 2) << 2), e);
  epi_write(acc, act, wbyte, r31, q1);
  bump(pub + w, lane);
}

// L2/L3: B from act slots (reverse rotation g = w, w-1, ... mod 8);
// asm A-pipeline (flag-free, crosses group boundaries).
static __device__ __forceinline__ void mlp_mid(
    char* __restrict__ act, int* pub, int* grp, int lane, int w, int q1, int r31,
    const char* __restrict__ Abase, const float* __restrict__ bias,
    int pub_tgt, int rbase, int wbyte, int gbase) {
  const int voff = lane * 16;
  const char* spA = Abase + w * 65536 + voff;

  floatx16 acc[2][4];
#pragma unroll
  for (int ol = 0; ol < 2; ++ol) {
    int fe0 = w * 64 + ol * 32 + 4 * q1;
#pragma unroll
    for (int g = 0; g < 4; ++g) {
      floatx4 bv = *(const floatx4*)(bias + fe0 + 8 * g);
#pragma unroll
      for (int nt = 0; nt < 4; ++nt) {
        acc[ol][nt][4 * g + 0] = bv[0];
        acc[ol][nt][4 * g + 1] = bv[1];
        acc[ol][nt][4 * g + 2] = bv[2];
        acc[ol][nt][4 * g + 3] = bv[3];
      }
    }
  }
  // A group bases: group i at spA + ((w-i)&7)*8192, kc j at +j*2048
  const char* apg  = spA + w * 8192;
  const char* apgN = spA + ((w - 1) & 7) * 8192;
  // B prologue: own group (g=w) slab 0 — self-published in program order.
  const char* gb = act + slot8(w, rbase) + voff;
  short8 b0 = *(const short8*)(gb);
  short8 b1v = *(const short8*)(gb + 1024);
  short8 b2 = *(const short8*)(gb + 2048);
  short8 b3 = *(const short8*)(gb + 3072);
  // asm A prologue: steps 0,1 of group w
  short8 aC0 = agl(apg);
  short8 aC1 = agl(apg + 1024);
  short8 aN0 = agl(apg + 2048);
  short8 aN1 = agl(apg + 3072);

#pragma unroll 1
  for (int i = 0; i < 8; ++i) {
#pragma unroll
    for (int j = 0; j < 4; ++j) {
      // A issue for step j+2 (flag-free; crosses group boundary)
      const char* apP;
      if (j < 2)      apP = apg + (j + 2) * 2048;
      else if (i < 7) apP = apgN + (j - 2) * 2048;  // j==2 -> +0, j==3 -> +2048
      else            apP = apg;                    // dead, in-bounds
      short8 aM0 = agl(apP);
      short8 aM1 = agl(apP + 1024);
      // B prefetch for step j+1 (flag-guarded at group boundary)
      const char* gbn = gb;
      const char* bsl;
      if (j < 3) {
        bsl = gb + (j + 1) * 4096;
      } else if (i < 7) {
        int g2 = (w - i - 1) & 7;
        waitge(pub + g2, pub_tgt);       // steady-state: long since satisfied
        gbn = act + slot8(g2, rbase) + voff;
        bsl = gbn;
      } else {
        bsl = gb;                        // dead prefetch, in-bounds
      }
      short8 bn0 = *(const short8*)(bsl);
      short8 bn1 = *(const short8*)(bsl + 1024);
      short8 bn2 = *(const short8*)(bsl + 2048);
      short8 bn3 = *(const short8*)(bsl + 3072);
      VMWAIT4();                                   // step-j pair retired
      __builtin_amdgcn_s_setprio(1);
      acc[0][0] = mfma32(aC0, b0, acc[0][0]);
      acc[0][1] = mfma32(aC0, b1v, acc[0][1]);
      acc[0][2] = mfma32(aC0, b2, acc[0][2]);
      acc[0][3] = mfma32(aC0, b3, acc[0][3]);
      acc[1][0] = mfma32(aC1, b0, acc[1][0]);
      acc[1][1] = mfma32(aC1, b1v, acc[1][1]);
      acc[1][2] = mfma32(aC1, b2, acc[1][2]);
      acc[1][3] = mfma32(aC1, b3, acc[1][3]);
      __builtin_amdgcn_s_setprio(0);
      aC0 = aN0; aC1 = aN1; aN0 = aM0; aN1 = aM1;
      b0 = bn0; b1v = bn1; b2 = bn2; b3 = bn3;
      gb = gbn;
    }
    apg = apgN;
    apgN = spA + ((w - i - 2) & 7) * 8192;  // base of group i+2
    bump_sig(grp + w, lane);             // group (w-i)&7 of this layer consumed
  }
  vmdrain4(aC0, aC1, aN0, aN1);          // in-flight dead pairs land

  // overwrite guard: victim = own input group (w+1)&7; readers = this layer.
  guard_grp(grp, w, gbase);
  epi_write(acc, act, wbyte, r31, q1);
  bump(pub + w, lane);
}

extern "C" __global__ __launch_bounds__(512) void fused_kernel(
    const char* __restrict__ ws, const float* __restrict__ b2,
    const float* __restrict__ b3, const float* __restrict__ b4,
    const float* __restrict__ ew, float* __restrict__ out) {
  extern __shared__ char smem[];
  char* act = smem;
  char* xreg = smem + X_OFF_L;
  int* l4c = (int*)(smem + SYNC_OFF);
  int* pub = l4c + 8;
  int* grp = l4c + 16;

  const int t = threadIdx.x, lane = t & 63, w = t >> 6;   // 8 waves
  const int q1 = lane >> 5, r31 = lane & 31;
  const int row0 = blockIdx.x << 7;      // 128-row tile, 256 blocks (1/CU)
  const int voff = lane * 16;

  if (t < 24) ((int*)(smem + SYNC_OFF))[t] = 0;

  // stage x: 16 units of 1KB; unit u: x-slab u>>2, nt u&3 (stride 4096)
  const ushort_t* xb = (const ushort_t*)(ws + XB_OFF);
#pragma unroll
  for (int s = 0; s < 2; ++s) {
    int u = w + 8 * s, v = u >> 2, nt = u & 3;
    ald16(xb + (row0 + nt * 32 + r31) * 64 + (2 * v + q1) * 8,
          xreg + v * 4096 + nt * 1024);
  }
  __syncthreads();                       // x staged (vmcnt drained) + flags 0

  // seed the inter-wave stagger: wave 7 first, ~450 cyc per index.
  for (int i = (7 - w) * 7; i > 0; --i) __builtin_amdgcn_s_sleep(1);

  const int rt = w & 3, kh = w >> 2;     // L4: row-tile, K-half
  const int row_l4 = row0 + rt * 32 + r31;
  floatx16 oacc[2] = {};

  for (int e = 0; e < 8; ++e) {
    int b1s = (3 * e + 1) & 7;           // L1-out frame (= L2 input frame)
    int b2s = (3 * e + 2) & 7;           // L2-out frame
    int b3s = (3 * e + 3) & 7;           // L3-out frame (= L4 input frame)

    mlp_l1(act, xreg, pub, l4c, lane, w, q1, r31,
           (const char*)ws + W1A_OFF + e * 65536,
           (const float*)(ws + B1E_OFF) + e * 512, slot8(w, b1s), e);
    mlp_mid(act, pub, grp, lane, w, q1, r31,
            (const char*)ws + W2A_OFF + e * 524288, b2 + e * 512,
            3 * e + 1, b1s, slot8(w, b2s), 16 * e);
    mlp_mid(act, pub, grp, lane, w, q1, r31,
            (const char*)ws + W3A_OFF + e * 524288, b3 + e * 512,
            3 * e + 2, b2s, slot8(w, b3s), 16 * e + 8);

    // L4: M=64 (both o4), N=32 (rows rt), K-half kh; groups descending;
    // asm A-pipeline; no act writes.
    {
      const char* spA4 = (const char*)ws + W4A_OFF + e * 65536 + voff;
      const float sc = ew[row_l4 * 8 + e];
      floatx16 acc4[2] = {};
      int g = 4 * kh + 3;
      const char* agb  = spA4 + g * 4096;      // group base (4 kc x 1024)
      const char* agbN = agb - 4096;           // next (descending) group base
      // asm A prologue: steps 0,1 of first group
      short8 aC0 = agl(agb);
      short8 aC1 = agl(agb + 32768);
      short8 aN0 = agl(agb + 1024);
      short8 aN1 = agl(agb + 32768 + 1024);
      waitge(pub + g, 3 * e + 3);
      const char* gb = act + slot8(g, b3s) + rt * 1024 + voff;
      short8 b = *(const short8*)(gb);
#pragma unroll 1
      for (int gl = 0; gl < 4; ++gl) {
#pragma unroll
        for (int j = 0; j < 4; ++j) {
          // A issue for step j+2 (flag-free)
          const char* apP;
          if (j < 2)       apP = agb + (j + 2) * 1024;
          else if (gl < 3) apP = agbN + (j - 2) * 1024;
          else             apP = agb;          // dead, in-bounds
          short8 aM0 = agl(apP);
          short8 aM1 = agl(apP + 32768);
          // B prefetch for step j+1 (flag-guarded at group boundary)
          const char* gbn = gb;
          const char* bsl;
          if (j < 3) {
            bsl = gb + (j + 1) * 4096;
          } else if (gl < 3) {
            waitge(pub + (g - 1), 3 * e + 3);
            gbn = act + slot8(g - 1, b3s) + rt * 1024 + voff;
            bsl = gbn;
          } else {
            bsl = gb;                    // dead prefetch, in-bounds
          }
          short8 bn = *(const short8*)(bsl);
          VMWAIT4();                     // step-j pair retired
          __builtin_amdgcn_s_setprio(1);
          acc4[0] = mfma32(aC0, b, acc4[0]);
          acc4[1] = mfma32(aC1, b, acc4[1]);
          __builtin_amdgcn_s_setprio(0);
          aC0 = aN0; aC1 = aN1; aN0 = aM0; aN1 = aM1;
          b = bn; gb = gbn;
        }
        g = g - 1; agb = agbN; agbN = agb - 4096;
      }
      vmdrain4(aC0, aC1, aN0, aN1);      // in-flight dead pairs land
      bump_sig(l4c + w, lane);           // L4(e) done: unblocks overwrites
      if (kh == 0) {
        const float* bp = b4 + e * 64;
#pragma unroll
        for (int ol = 0; ol < 2; ++ol) {
          int fe0 = ol * 32 + 4 * q1;
#pragma unroll
          for (int g2 = 0; g2 < 4; ++g2) {
            floatx4 bv = *(const floatx4*)(bp + fe0 + 8 * g2);
            oacc[ol][4 * g2 + 0] += sc * (acc4[ol][4 * g2 + 0] + bv[0]);
            oacc[ol][4 * g2 + 1] += sc * (acc4[ol][4 * g2 + 1] + bv[1]);
            oacc[ol][4 * g2 + 2] += sc * (acc4[ol][4 * g2 + 2] + bv[2]);
            oacc[ol][4 * g2 + 3] += sc * (acc4[ol][4 * g2 + 3] + bv[3]);
          }
        }
      } else {
#pragma unroll
        for (int ol = 0; ol < 2; ++ol)
#pragma unroll
          for (int i = 0; i < 16; ++i) oacc[ol][i] += sc * acc4[ol][i];
      }
    }
  }

  // final: merge K-half partners (w, w+4) via LDS (act dead), plain stores
  __syncthreads();
  if (kh == 1) {
#pragma unroll
    for (int ol = 0; ol < 2; ++ol)
#pragma unroll
      for (int g = 0; g < 4; ++g) {
        floatx4 p = {oacc[ol][4 * g + 0], oacc[ol][4 * g + 1],
                     oacc[ol][4 * g + 2], oacc[ol][4 * g + 3]};
        *(floatx4*)(act + rt * 8192 + ol * 4096 + g * 1024 + lane * 16) = p;
      }
  }
  __syncthreads();
  if (kh == 0) {
    float* orow = out + (size_t)row_l4 * 64;
#pragma unroll
    for (int ol = 0; ol < 2; ++ol)
#pragma unroll
      for (int g = 0; g < 4; ++g) {
        floatx4 p = *(const floatx4*)(act + rt * 8192 + ol * 4096 + g * 1024 + lane * 16);
        floatx4 v = {oacc[ol][4 * g + 0] + p[0], oacc[ol][4 * g + 1] + p[1],
                     oacc[ol][4 * g + 2] + p[2], oacc[ol][4 * g + 3] + p[3]};
        *(floatx4*)(orow + ol * 32 + 8 * g + 4 * q1) = v;
      }
  }
}

extern "C" void kernel_launch(void* const* d_in, const int* in_sizes, int n_in,
                              void* d_out, int out_size, void* d_ws, size_t ws_size,
                              hipStream_t stream) {
  const float* t  = (const float*)d_in[0];
  const float* x  = (const float*)d_in[1];
  const float* ew = (const float*)d_in[2];
  const float* om = (const float*)d_in[3];
  const float* W1 = (const float*)d_in[4];
  const float* b1 = (const float*)d_in[5];
  const float* W2 = (const float*)d_in[6];
  const float* b2 = (const float*)d_in[7];
  const float* W3 = (const float*)d_in[8];
  const float* b3 = (const float*)d_in[9];
  const float* W4 = (const float*)d_in[10];
  const float* b4 = (const float*)d_in[11];
  char* ws = (char*)d_ws;
  float* out = (float*)d_out;
  (void)in_sizes; (void)n_in; (void)ws_size; (void)out_size;

  static int smem_set = 0;
  if (!smem_set) {
    hipFuncSetAttribute((const void*)fused_kernel,
                        hipFuncAttributeMaxDynamicSharedMemorySize, SMEM_SZ);
    smem_set = 1;
  }
  // no memset: fused_kernel writes every element of out with plain stores
  prep_kernel<<<3344, 256, 0, stream>>>(t, x, om, W1, b1, W2, W3, W4, ws);
  fused_kernel<<<256, 512, SMEM_SZ, stream>>>(ws, b2, b3, b4, ew, out);
}